// Round 8
// baseline (349.905 us; speedup 1.0000x reference)
//
#include <hip/hip_runtime.h>

// MQA: B=2, S=2048, HID=2048, NH=16, HD=128
#define B_   2
#define S_   2048
#define HID_ 2048
#define NH_  16
#define HD_  128
#define M_   (B_ * S_)   // 4096 total rows

using half4   = __attribute__((ext_vector_type(4))) _Float16;
using half8   = __attribute__((ext_vector_type(8))) _Float16;
using floatx4 = __attribute__((ext_vector_type(4))) float;

// async global->LDS, 16B per lane (LDS dst = wave-uniform base + lane*16)
__device__ __forceinline__ void gl_lds16(const void* g, void* l) {
  __builtin_amdgcn_global_load_lds(
      (const __attribute__((address_space(1))) void*)g,
      (__attribute__((address_space(3))) void*)l, 16, 0, 0);
}

__device__ __forceinline__ void cvt8(const float* s, _Float16* d, int i) {
  const floatx4* sp = (const floatx4*)s;
  floatx4 a = sp[(size_t)i * 2];
  floatx4 b = sp[(size_t)i * 2 + 1];
  half8 h;
  h[0] = (_Float16)a[0]; h[1] = (_Float16)a[1];
  h[2] = (_Float16)a[2]; h[3] = (_Float16)a[3];
  h[4] = (_Float16)b[0]; h[5] = (_Float16)b[1];
  h[6] = (_Float16)b[2]; h[7] = (_Float16)b[3];
  *(half8*)(d + (size_t)i * 8) = h;
}

// ---------------------------------------------------------------------------
// One fused fp32->fp16 cast for hidden + all 4 weights (2048 elems/blk)
// ---------------------------------------------------------------------------
__global__ __launch_bounds__(256) void cvt_all(
    const float* __restrict__ h,  const float* __restrict__ wq,
    const float* __restrict__ wk, const float* __restrict__ wv,
    const float* __restrict__ wo,
    _Float16* __restrict__ dh,  _Float16* __restrict__ dwq,
    _Float16* __restrict__ dwk, _Float16* __restrict__ dwv,
    _Float16* __restrict__ dwo) {
  int bid = blockIdx.x;
  const float* s;
  _Float16* d;
  int off;
  if (bid < 4096)      { s = h;  d = dh;  off = bid; }
  else if (bid < 6144) { s = wq; d = dwq; off = bid - 4096; }
  else if (bid < 6272) { s = wk; d = dwk; off = bid - 6144; }
  else if (bid < 6400) { s = wv; d = dwv; off = bid - 6272; }
  else                 { s = wo; d = dwo; off = bid - 6400; }
  cvt8(s, d, off * 256 + threadIdx.x);
}

// ---------------------------------------------------------------------------
// GEMM body, round-16: 128(M)x256(N) tile, BK=64, 8 waves (2M x 4N),
// double-buffered LDS + COUNTED-VMCNT schedule (T4, m201 primitive pair):
//   stage(next: 6 gl_lds) -> s_waitcnt vmcnt(6) -> raw s_barrier ->
//   sched_barrier(0) -> setprio(1) 32 MFMA setprio(0) -> sched_barrier(0)
//   -> raw s_barrier
// Round-7 POST-MORTEM: with __syncthreads(), the compiler's auto-drain
// (vmcnt(0) before s_barrier) waited for the 6 loads issued THIS iteration
// -> full L2/L3 latency (~200-900 cyc) serialized into every K-step,
// nullifying the double buffer (T3's gain IS T4, m218). vmcnt(6) keeps
// next-tile loads in flight across the barrier; per-wave FIFO retirement
// (m135) makes "oldest 6 done" == "current buffer ready". Barrier-2
// guarantees all waves consumed buf cur into regs before re-staging it.
// Final iteration drains with vmcnt(0).
// SETTLED (do NOT redo): round-14 2-phase at 128x128 (+15-20 us, LDS-
// occupancy loss); 32x32x16 MFMA (ds_read conflicts); template-duplicated
// __shared__ (round-6 compile fail -> hoisted GemmSmem).
// MODE: 0 = fp16 out (Q tiles), 1 = fused K|V tile (K normal + V
// transposed), 2 = fp32 out (output projection). K = HID_ = 2048 always.
// ---------------------------------------------------------------------------
struct GemmSmem {
  _Float16 As[2][2][128][32];  // 32 KB
  _Float16 Bs[2][2][256][32];  // 64 KB
};

template <int MODE, typename OutT>
__device__ __forceinline__ void gemm256_body(
    GemmSmem* sm,
    const _Float16* __restrict__ A,    // [M][2048]
    const _Float16* __restrict__ W0,   // weight rows for tile cols 0..127
    const _Float16* __restrict__ W1,   // weight rows for tile cols 128..255
    const float* __restrict__ biasA,   // bias for tile cols 0..127
    const float* __restrict__ biasB,   // bias for tile cols 128..255
    OutT* __restrict__ C, _Float16* __restrict__ CT,  // CT: V^T (MODE 1)
    int Nout, int m0, int c0) {
  const int tid  = threadIdx.x;
  const int lane = tid & 63;
  const int wave = tid >> 6;          // 0..7
  const int wm   = wave >> 2;         // 0..1  (64-row group)
  const int wn   = wave & 3;          // 0..3  (64-col group)
  const int l15  = lane & 15, lq = lane >> 4;
  const int wrow = wave * 16;         // wave-uniform LDS row base

  floatx4 acc[4][4];
#pragma unroll
  for (int i = 0; i < 4; i++)
#pragma unroll
    for (int j = 0; j < 4; j++) acc[i][j] = (floatx4){0.f, 0.f, 0.f, 0.f};

  const int srow = tid >> 2;          // 0..127 staging row
  const int scol = (tid & 3) * 8;     // halves within 32-half slice
  const _Float16* Ag  = A  + (size_t)(m0 + srow) * HID_ + scol;
  const _Float16* W0g = W0 + (size_t)srow * HID_ + scol;
  const _Float16* W1g = W1 + (size_t)srow * HID_ + scol;

  auto stage = [&](int bufi, int kt) {
#pragma unroll
    for (int s = 0; s < 2; s++) {
      gl_lds16(Ag  + kt + s * 32, &sm->As[bufi][s][wrow][0]);
      gl_lds16(W0g + kt + s * 32, &sm->Bs[bufi][s][wrow][0]);
      gl_lds16(W1g + kt + s * 32, &sm->Bs[bufi][s][128 + wrow][0]);
    }
  };
  auto compute = [&](int bufi) {
#pragma unroll
    for (int s = 0; s < 2; s++) {
      half8 af[4], bf[4];
#pragma unroll
      for (int i = 0; i < 4; i++)
        af[i] = *(const half8*)&sm->As[bufi][s][wm * 64 + i * 16 + l15][lq * 8];
#pragma unroll
      for (int j = 0; j < 4; j++)
        bf[j] = *(const half8*)&sm->Bs[bufi][s][wn * 64 + j * 16 + l15][lq * 8];
#pragma unroll
      for (int i = 0; i < 4; i++)
#pragma unroll
        for (int j = 0; j < 4; j++)
          acc[i][j] = __builtin_amdgcn_mfma_f32_16x16x32_f16(af[i], bf[j], acc[i][j], 0, 0, 0);
    }
  };

  // prologue: tile 0 -> buf0 (6 loads in flight)
  stage(0, 0);

  for (int kt = 0; kt < HID_; kt += 64) {
    const int cur = (kt >> 6) & 1;
    if (kt + 64 < HID_) {
      stage(cur ^ 1, kt + 64);   // 6 more in flight (12 total)
      asm volatile("s_waitcnt vmcnt(6)" ::: "memory");  // cur's 6 done; next stays in flight
    } else {
      asm volatile("s_waitcnt vmcnt(0)" ::: "memory");  // final: drain
    }
    __builtin_amdgcn_s_barrier();          // all waves' cur-loads landed
    __builtin_amdgcn_sched_barrier(0);     // fence: no ds_read hoists above
    __builtin_amdgcn_s_setprio(1);
    compute(cur);                          // ds_read + 32 MFMA (compiler lgkm waits)
    __builtin_amdgcn_s_setprio(0);
    __builtin_amdgcn_sched_barrier(0);     // fence: no next-stage sinks above
    __builtin_amdgcn_s_barrier();          // cur fully consumed -> safe to re-stage
  }

  // ---- epilogue
  const int rq = lq * 4;
#pragma unroll
  for (int j = 0; j < 4; j++) {
    const int colt = wn * 64 + j * 16 + l15;       // 0..255 within tile
    if (MODE != 1 || colt < 128) {
      // normal store (Q tiles, K half of the KV tile, out projection)
      float bv = (colt < 128) ? biasA[colt] : biasB[colt - 128];
#pragma unroll
      for (int i = 0; i < 4; i++) {
        int row = m0 + wm * 64 + i * 16 + rq;
#pragma unroll
        for (int r = 0; r < 4; r++)
          C[(size_t)(row + r) * Nout + c0 + colt] = (OutT)(acc[i][j][r] + bv);
      }
    } else {
      // V half of the KV tile: store transposed as V^T[b][col][s]
      const int colv = colt - 128;
      float bv = biasB[colv];
      const int bb = m0 / S_;
      const int sb = m0 - bb * S_ + wm * 64;
#pragma unroll
      for (int i = 0; i < 4; i++) {
        half4 o;
#pragma unroll
        for (int r = 0; r < 4; r++) o[r] = (_Float16)(acc[i][j][r] + bv);
        *(half4*)(CT + (size_t)bb * HD_ * S_ + (size_t)colv * S_
                  + sb + i * 16 + rq) = o;
      }
    }
  }
}

// Fused Q/K/V projection: grid.x = 9 column tiles (8 Q tiles + 1 fused K|V)
__global__ __launch_bounds__(512, 2) void gemm_qkv(
    const _Float16* __restrict__ A,
    const _Float16* __restrict__ Wq, const float* __restrict__ bq, _Float16* __restrict__ Qh,
    const _Float16* __restrict__ Wk, const float* __restrict__ bk, _Float16* __restrict__ Kh,
    const _Float16* __restrict__ Wv, const float* __restrict__ bv, _Float16* __restrict__ VhT) {
  __shared__ __align__(16) GemmSmem sm;  // 96 KB, shared by both branches
  const int nt = blockIdx.x, m0 = blockIdx.y * 128;
  if (nt < 8)
    gemm256_body<0, _Float16>(&sm, A, Wq + (size_t)nt * 256 * HID_,
                              Wq + (size_t)(nt * 256 + 128) * HID_,
                              bq + nt * 256, bq + nt * 256 + 128,
                              Qh, nullptr, HID_, m0, nt * 256);
  else
    gemm256_body<1, _Float16>(&sm, A, Wk, Wv, bk, bv, Kh, VhT, HD_, m0, 0);
}

__global__ __launch_bounds__(512, 2) void gemm_out(
    const _Float16* __restrict__ A, const _Float16* __restrict__ W,
    const float* __restrict__ bias, float* __restrict__ C) {
  __shared__ __align__(16) GemmSmem sm;  // 96 KB
  const int n0 = blockIdx.x * 256, m0 = blockIdx.y * 128;
  gemm256_body<2, float>(&sm, A, W + (size_t)n0 * HID_, W + (size_t)(n0 + 128) * HID_,
                         bias + n0, bias + n0 + 128, C, nullptr, HID_, m0, n0);
}

// ---------------------------------------------------------------------------
// MFMA flash attention — round-3 version, verified 108-111 us (round-0
// structure + T13 defer-max THR=8). 256 thr / 4 waves x 32 q-rows, full
// 64-wide KV per wave, S^T formulation, dbuf K/V LDS, one barrier/tile.
// SETTLED (do NOT redo):
//  - round-12: 64-row blocks double total staging -> MfmaUtil 39->33, +18 us.
//  - round-13: body needs ~180 unified VGPRs/wave; ANY geometry needing
//    >=4 waves/SIMD (<=128 regs) spills ~1.4 GB scratch (dur 429 us).
//    2 waves/SIMD is structural for this body. Do not widen blocks.
//  - round-8: (256,4) launch bounds -> same spill failure.
// ---------------------------------------------------------------------------
__global__ __launch_bounds__(256, 2) void attn_mfma(
    const _Float16* __restrict__ Q, const _Float16* __restrict__ K,
    const _Float16* __restrict__ VhT, const int* __restrict__ mask,
    _Float16* __restrict__ Obuf) {
  constexpr int BN = 64, KP = 136, VP = 72, NT = S_ / BN;
  __shared__ __align__(16) _Float16 Ks[2][BN][KP];   // 34.8 KB
  __shared__ __align__(16) _Float16 Vt[2][HD_][VP];  // 36.9 KB

  const int tid  = threadIdx.x;
  const int lane = tid & 63, wave = tid >> 6;
  const int l15  = lane & 15, lq = lane >> 4;
  const int q0   = blockIdx.x * 128;
  const int b    = blockIdx.y >> 4, h = blockIdx.y & 15;
  const float sl2e = 0.08838834764831845f * 1.44269504088896341f;  // scale*log2e
  const _Float16* VT = VhT + (size_t)b * HD_ * S_;
  const _Float16* Kb = K + (size_t)b * S_ * HD_;
  const int* mb = mask + b * S_;

  int krow[4], kcol[4], vrow[4], vcol[4];
#pragma unroll
  for (int it = 0; it < 4; it++) {
    int i = it * 256 + tid;
    krow[it] = i >> 4;  kcol[it] = (i & 15) * 8;
    vrow[it] = i >> 3;  vcol[it] = (i & 7) * 8;
  }

  // Q fragments (B-operand of S^T mfma): m=l15, d=lq*8+j
  half8 qf[2][4];
#pragma unroll
  for (int i = 0; i < 2; i++)
#pragma unroll
    for (int kd = 0; kd < 4; kd++)
      qf[i][kd] = *(const half8*)(Q + (size_t)(b * S_ + q0 + wave * 32 + i * 16 + l15) * HID_
                                  + h * HD_ + kd * 32 + lq * 8);

  float m_i[2] = {-3.0e38f, -3.0e38f};
  float l_p[2] = {0.f, 0.f};   // per-lane partial of l
  floatx4 oacc[2][8];
#pragma unroll
  for (int i = 0; i < 2; i++)
#pragma unroll
    for (int jd = 0; jd < 8; jd++) oacc[i][jd] = (floatx4){0.f, 0.f, 0.f, 0.f};

  half8 kreg[4], vreg[4];
  // prologue: tile 0 -> regs -> buf 0
#pragma unroll
  for (int it = 0; it < 4; it++) {
    kreg[it] = *(const half8*)(Kb + (size_t)krow[it] * HD_ + kcol[it]);
    vreg[it] = *(const half8*)(VT + (size_t)vrow[it] * S_ + vcol[it]);
  }
#pragma unroll
  for (int it = 0; it < 4; it++) {
    *(half8*)&Ks[0][krow[it]][kcol[it]] = kreg[it];
    *(half8*)&Vt[0][vrow[it]][vcol[it]] = vreg[it];
  }
  __syncthreads();

  for (int t = 0; t < NT; t++) {
    const int cur = t & 1;
    const int n0  = t * BN;
    const bool has_next = (t + 1) < NT;

    if (has_next) {
      const int nn = n0 + BN;
#pragma unroll
      for (int it = 0; it < 4; it++) {
        kreg[it] = *(const half8*)(Kb + (size_t)(nn + krow[it]) * HD_ + kcol[it]);
        vreg[it] = *(const half8*)(VT + (size_t)vrow[it] * S_ + nn + vcol[it]);
      }
    }

    int4 mk4[4];
#pragma unroll
    for (int j = 0; j < 4; j++)
      mk4[j] = *(const int4*)(mb + n0 + j * 16 + lq * 4);

    // ---- S^T = K Q^T : st[j][i], n = j*16+lq*4+r, m = i*16+l15 (+wave*32)
    floatx4 st[4][2];
#pragma unroll
    for (int j = 0; j < 4; j++)
#pragma unroll
      for (int i = 0; i < 2; i++) st[j][i] = (floatx4){0.f, 0.f, 0.f, 0.f};
#pragma unroll
    for (int kd = 0; kd < 4; kd++) {
      half8 kb[4];
#pragma unroll
      for (int j = 0; j < 4; j++)
        kb[j] = *(const half8*)&Ks[cur][j * 16 + l15][kd * 32 + lq * 8];
#pragma unroll
      for (int j = 0; j < 4; j++)
#pragma unroll
        for (int i = 0; i < 2; i++)
          st[j][i] = __builtin_amdgcn_mfma_f32_16x16x32_f16(kb[j], qf[i][kd], st[j][i], 0, 0, 0);
    }

    floatx4 amf[4];
#pragma unroll
    for (int j = 0; j < 4; j++) {
      amf[j][0] = mk4[j].x ? 0.f : -3.0e38f;
      amf[j][1] = mk4[j].y ? 0.f : -3.0e38f;
      amf[j][2] = mk4[j].z ? 0.f : -3.0e38f;
      amf[j][3] = mk4[j].w ? 0.f : -3.0e38f;
    }

    // ---- online softmax (2 shfls for max; defer-max THR=8; l as lane partial)
    half4 ph[2][4];
#pragma unroll
    for (int i = 0; i < 2; i++) {
      float mx = -3.0e38f;
#pragma unroll
      for (int j = 0; j < 4; j++)
#pragma unroll
        for (int r = 0; r < 4; r++) {
          float v = st[j][i][r] * sl2e + amf[j][r];
          st[j][i][r] = v;
          mx = fmaxf(mx, v);
        }
      mx = fmaxf(mx, __shfl_xor(mx, 16));
      mx = fmaxf(mx, __shfl_xor(mx, 32));
      if (!__all(mx <= m_i[i] + 8.0f)) {
        float mnew  = fmaxf(m_i[i], mx);
        float alpha = __builtin_amdgcn_exp2f(m_i[i] - mnew);
        m_i[i] = mnew;
        l_p[i] *= alpha;
#pragma unroll
        for (int r = 0; r < 4; r++) {
          float a_r = __shfl(alpha, lq * 4 + r);
#pragma unroll
          for (int jd = 0; jd < 8; jd++) oacc[i][jd][r] *= a_r;
        }
      }
      float rs = 0.f;
#pragma unroll
      for (int j = 0; j < 4; j++)
#pragma unroll
        for (int r = 0; r < 4; r++) {
          float pv = __builtin_amdgcn_exp2f(st[j][i][r] - m_i[i]);
          ph[i][j][r] = (_Float16)pv;
          rs += pv;
        }
      l_p[i] += rs;
    }

    // ---- O += P V via 16x16x16 (A = ph in-register, B = Vt half4)
#pragma unroll
    for (int j = 0; j < 4; j++) {
#pragma unroll
      for (int jd = 0; jd < 8; jd++) {
        half4 vb = *(const half4*)&Vt[cur][jd * 16 + l15][j * 16 + lq * 4];
#pragma unroll
        for (int i = 0; i < 2; i++)
          oacc[i][jd] = __builtin_amdgcn_mfma_f32_16x16x16f16(ph[i][j], vb, oacc[i][jd], 0, 0, 0);
      }
    }

    if (has_next) {
      const int nxt = 1 - cur;
#pragma unroll
      for (int it = 0; it < 4; it++) {
        *(half8*)&Ks[nxt][krow[it]][kcol[it]] = kreg[it];
        *(half8*)&Vt[nxt][vrow[it]][vcol[it]] = vreg[it];
      }
    }
    __syncthreads();
  }

  // ---- final l reduction + epilogue
#pragma unroll
  for (int i = 0; i < 2; i++) {
    float l = l_p[i];
    l += __shfl_xor(l, 16);
    l += __shfl_xor(l, 32);
    float linv = 1.0f / l;
#pragma unroll
    for (int r = 0; r < 4; r++) {
      float lr = __shfl(linv, lq * 4 + r);
      size_t row = (size_t)(b * S_ + q0 + wave * 32 + i * 16 + lq * 4 + r);
#pragma unroll
      for (int jd = 0; jd < 8; jd++)
        Obuf[row * HID_ + h * HD_ + jd * 16 + l15] = (_Float16)(oacc[i][jd][r] * lr);
    }
  }
}

// ---------------------------------------------------------------------------
extern "C" void kernel_launch(void* const* d_in, const int* in_sizes, int n_in,
                              void* d_out, int out_size, void* d_ws, size_t ws_size,
                              hipStream_t stream) {
  const float* hidden = (const float*)d_in[0];
  const int*   mask   = (const int*)d_in[1];
  const float* Wq = (const float*)d_in[2];
  const float* bq = (const float*)d_in[3];
  const float* Wk = (const float*)d_in[4];
  const float* bk = (const float*)d_in[5];
  const float* Wv = (const float*)d_in[6];
  const float* bv = (const float*)d_in[7];
  const float* Wo = (const float*)d_in[8];
  const float* bo = (const float*)d_in[9];
  float* out = (float*)d_out;

  char* p = (char*)d_ws;
  auto alloc = [&](size_t bytes) {
    char* r = p;
    p += (bytes + 255) & ~(size_t)255;
    return r;
  };
  _Float16* hidh  = (_Float16*)alloc((size_t)M_ * HID_ * 2);
  _Float16* Wqh   = (_Float16*)alloc((size_t)HID_ * HID_ * 2);
  _Float16* Wkh   = (_Float16*)alloc((size_t)HD_ * HID_ * 2);
  _Float16* Wvh   = (_Float16*)alloc((size_t)HD_ * HID_ * 2);
  _Float16* Woh   = (_Float16*)alloc((size_t)HID_ * HID_ * 2);
  _Float16* Qh    = (_Float16*)alloc((size_t)M_ * HID_ * 2);
  _Float16* Kh    = (_Float16*)alloc((size_t)M_ * HD_ * 2);
  _Float16* VhT   = (_Float16*)alloc((size_t)M_ * HD_ * 2);
  _Float16* attnh = (_Float16*)alloc((size_t)M_ * HID_ * 2);

  // one fused fp32 -> fp16 cast (8448 blocks)
  cvt_all<<<8448, 256, 0, stream>>>(hidden, Wq, Wk, Wv, Wo,
                                    hidh, Wqh, Wkh, Wvh, Woh);

  // fused Q/K/V projection (V written transposed): 9 x 32 tiles, 512 thr
  dim3 gqkv(9, M_ / 128);
  gemm_qkv<<<gqkv, 512, 0, stream>>>(hidh, Wqh, bq, Qh, Wkh, bk, Kh, Wvh, bv, VhT);

  // attention (S^T flash, dbuf K/V): 128 q-rows/block, 4 waves
  dim3 ga(S_ / 128, B_ * NH_);  // (16, 32)
  attn_mfma<<<ga, 256, 0, stream>>>(Qh, Kh, VhT, mask, attnh);

  // output projection -> d_out (fp32): 8 x 32 tiles, 512 thr
  dim3 go(HID_ / 256, M_ / 128);
  gemm_out<<<go, 512, 0, stream>>>(attnh, Woh, bo, out);
}

// Round 9
// 314.178 us; speedup vs baseline: 1.1137x; 1.1137x over previous
//
#include <hip/hip_runtime.h>

// MQA: B=2, S=2048, HID=2048, NH=16, HD=128
#define B_   2
#define S_   2048
#define HID_ 2048
#define NH_  16
#define HD_  128
#define M_   (B_ * S_)   // 4096 total rows

using half4   = __attribute__((ext_vector_type(4))) _Float16;
using half8   = __attribute__((ext_vector_type(8))) _Float16;
using floatx4 = __attribute__((ext_vector_type(4))) float;

// async global->LDS, 16B per lane (LDS dst = wave-uniform base + lane*16)
__device__ __forceinline__ void gl_lds16(const void* g, void* l) {
  __builtin_amdgcn_global_load_lds(
      (const __attribute__((address_space(1))) void*)g,
      (__attribute__((address_space(3))) void*)l, 16, 0, 0);
}

__device__ __forceinline__ void cvt8(const float* s, _Float16* d, int i) {
  const floatx4* sp = (const floatx4*)s;
  floatx4 a = sp[(size_t)i * 2];
  floatx4 b = sp[(size_t)i * 2 + 1];
  half8 h;
  h[0] = (_Float16)a[0]; h[1] = (_Float16)a[1];
  h[2] = (_Float16)a[2]; h[3] = (_Float16)a[3];
  h[4] = (_Float16)b[0]; h[5] = (_Float16)b[1];
  h[6] = (_Float16)b[2]; h[7] = (_Float16)b[3];
  *(half8*)(d + (size_t)i * 8) = h;
}

// ---------------------------------------------------------------------------
// One fused fp32->fp16 cast for hidden + all 4 weights (2048 elems/blk)
// ---------------------------------------------------------------------------
__global__ __launch_bounds__(256) void cvt_all(
    const float* __restrict__ h,  const float* __restrict__ wq,
    const float* __restrict__ wk, const float* __restrict__ wv,
    const float* __restrict__ wo,
    _Float16* __restrict__ dh,  _Float16* __restrict__ dwq,
    _Float16* __restrict__ dwk, _Float16* __restrict__ dwv,
    _Float16* __restrict__ dwo) {
  int bid = blockIdx.x;
  const float* s;
  _Float16* d;
  int off;
  if (bid < 4096)      { s = h;  d = dh;  off = bid; }
  else if (bid < 6144) { s = wq; d = dwq; off = bid - 4096; }
  else if (bid < 6272) { s = wk; d = dwk; off = bid - 6144; }
  else if (bid < 6400) { s = wv; d = dwv; off = bid - 6272; }
  else                 { s = wo; d = dwo; off = bid - 6400; }
  cvt8(s, d, off * 256 + threadIdx.x);
}

// ---------------------------------------------------------------------------
// GEMM body — ROUND-0 VERSION RESTORED (verified best: non-attn 209 us).
// C[M,N] = A[M,K] @ W[N,K]^T + bias. 128x128 tile, BK=32, unpadded 32-half
// LDS rows, global_load_lds width=16 staging, 16x16x32 MFMA.
// GEMM LEDGER (this session, non-attn totals — do NOT redo):
//   round-0 128²/BK32 single-buf 2-barrier:            209 us  <- best
//   round-3 128² fake-2-phase (same barrier rate):     223 us
//   round-7 256-wide BK64, 1 draining barrier/K-tile:  227 us
//   round-8 256-wide counted-vmcnt + sched_barrier(0): 239 us
//     (m141/m196 failure mode: coarse phase-split + order-pinning defeats
//      the compiler's fine ds_read/MFMA interleave. Counted-vmcnt only pays
//      with the full m201 8-phase fine interleave — a separate rewrite.)
// Also settled earlier: BK=64 at 128² (+7 us), 32x32x16 MFMA (+27 us).
// TRANS: store transposed as C[b][col][s] (for V^T).
// ---------------------------------------------------------------------------
template <typename OutT, bool TRANS>
__device__ __forceinline__ void gemm128_body(
    const _Float16* __restrict__ A, const _Float16* __restrict__ W,
    const float* __restrict__ bias, OutT* __restrict__ C,
    int Nout, int K, int m0, int n0w, int c0) {
  __shared__ __align__(16) _Float16 As[128][32];  // 8 KB
  __shared__ __align__(16) _Float16 Ws[128][32];

  const int tid  = threadIdx.x;
  const int lane = tid & 63;
  const int wave = tid >> 6;
  const int wm   = wave >> 1, wn = wave & 1;
  const int l15  = lane & 15, lq = lane >> 4;
  const int srow = wave * 16 + (lane >> 2);
  const int scol = (lane & 3) * 8;

  floatx4 acc[4][4];
#pragma unroll
  for (int i = 0; i < 4; i++)
#pragma unroll
    for (int j = 0; j < 4; j++) acc[i][j] = (floatx4){0.f, 0.f, 0.f, 0.f};

  const _Float16* Ag = A + (size_t)(m0 + srow) * K + scol;
  const _Float16* Wg = W + (size_t)(n0w + srow) * K + scol;
  const size_t step64 = (size_t)64 * K;

  for (int kt = 0; kt < K; kt += 32) {
    gl_lds16(Ag + kt,          &As[wave * 16][0]);
    gl_lds16(Ag + step64 + kt, &As[64 + wave * 16][0]);
    gl_lds16(Wg + kt,          &Ws[wave * 16][0]);
    gl_lds16(Wg + step64 + kt, &Ws[64 + wave * 16][0]);
    __syncthreads();

    half8 af[4], bf[4];
#pragma unroll
    for (int i = 0; i < 4; i++)
      af[i] = *(const half8*)&As[wm * 64 + i * 16 + l15][lq * 8];
#pragma unroll
    for (int j = 0; j < 4; j++)
      bf[j] = *(const half8*)&Ws[wn * 64 + j * 16 + l15][lq * 8];
#pragma unroll
    for (int i = 0; i < 4; i++)
#pragma unroll
      for (int j = 0; j < 4; j++)
        acc[i][j] = __builtin_amdgcn_mfma_f32_16x16x32_f16(af[i], bf[j], acc[i][j], 0, 0, 0);
    __syncthreads();
  }

  const int rq = lq * 4;
  if constexpr (TRANS) {
    const int b  = m0 / S_;
    const int sb = m0 - b * S_ + wm * 64;
#pragma unroll
    for (int j = 0; j < 4; j++) {
      int col  = wn * 64 + j * 16 + l15;
      float bv = bias[n0w + col];
#pragma unroll
      for (int i = 0; i < 4; i++) {
        half4 o;
#pragma unroll
        for (int r = 0; r < 4; r++) o[r] = (_Float16)(acc[i][j][r] + bv);
        *(half4*)((_Float16*)C + (size_t)b * HD_ * S_ + (size_t)col * S_
                  + sb + i * 16 + rq) = o;
      }
    }
  } else {
#pragma unroll
    for (int j = 0; j < 4; j++) {
      int col_l = wn * 64 + j * 16 + l15;
      float bv  = bias[n0w + col_l];
#pragma unroll
      for (int i = 0; i < 4; i++) {
        int row = m0 + wm * 64 + i * 16 + rq;
#pragma unroll
        for (int r = 0; r < 4; r++)
          C[(size_t)(row + r) * Nout + c0 + col_l] = (OutT)(acc[i][j][r] + bv);
      }
    }
  }
}

// Fused Q/K/V projection: grid.x = 18 column tiles (16 Q + 1 K + 1 V->V^T)
__global__ __launch_bounds__(256) void gemm_qkv(
    const _Float16* __restrict__ A,
    const _Float16* __restrict__ Wq, const float* __restrict__ bq, _Float16* __restrict__ Qh,
    const _Float16* __restrict__ Wk, const float* __restrict__ bk, _Float16* __restrict__ Kh,
    const _Float16* __restrict__ Wv, const float* __restrict__ bv, _Float16* __restrict__ VhT) {
  const int nt = blockIdx.x, m0 = blockIdx.y * 128;
  if (nt < 16)
    gemm128_body<_Float16, false>(A, Wq, bq, Qh, HID_, HID_, m0, nt * 128, nt * 128);
  else if (nt == 16)
    gemm128_body<_Float16, false>(A, Wk, bk, Kh, HD_, HID_, m0, 0, 0);
  else
    gemm128_body<_Float16, true>(A, Wv, bv, VhT, HD_, HID_, m0, 0, 0);
}

__global__ __launch_bounds__(256) void gemm_out(
    const _Float16* __restrict__ A, const _Float16* __restrict__ W,
    const float* __restrict__ bias, float* __restrict__ C) {
  gemm128_body<float, false>(A, W, bias, C, HID_, HID_, blockIdx.y * 128,
                             blockIdx.x * 128, blockIdx.x * 128);
}

// ---------------------------------------------------------------------------
// MFMA flash attention — round-3/7 version, verified 108.3-111.0 us
// (round-0 structure + T13 defer-max THR=8). 256 thr / 4 waves x 32 q-rows,
// full 64-wide KV per wave, S^T formulation, dbuf K/V LDS, register
// prefetch, one barrier per KV tile, deferred l reduction.
// SETTLED (do NOT redo):
//  - round-12: 64-row blocks double total staging -> MfmaUtil 39->33, +18 us.
//  - round-13: body needs ~180 unified VGPRs/wave; ANY geometry needing
//    >=4 waves/SIMD (<=128 regs) spills ~1.4 GB scratch (dur 429 us).
//    2 waves/SIMD is structural for this body. Do not widen blocks.
//  - round-8 (prev session): (256,4) launch bounds -> same spill failure.
// ---------------------------------------------------------------------------
__global__ __launch_bounds__(256, 2) void attn_mfma(
    const _Float16* __restrict__ Q, const _Float16* __restrict__ K,
    const _Float16* __restrict__ VhT, const int* __restrict__ mask,
    _Float16* __restrict__ Obuf) {
  constexpr int BN = 64, KP = 136, VP = 72, NT = S_ / BN;
  __shared__ __align__(16) _Float16 Ks[2][BN][KP];   // 34.8 KB
  __shared__ __align__(16) _Float16 Vt[2][HD_][VP];  // 36.9 KB

  const int tid  = threadIdx.x;
  const int lane = tid & 63, wave = tid >> 6;
  const int l15  = lane & 15, lq = lane >> 4;
  const int q0   = blockIdx.x * 128;
  const int b    = blockIdx.y >> 4, h = blockIdx.y & 15;
  const float sl2e = 0.08838834764831845f * 1.44269504088896341f;  // scale*log2e
  const _Float16* VT = VhT + (size_t)b * HD_ * S_;
  const _Float16* Kb = K + (size_t)b * S_ * HD_;
  const int* mb = mask + b * S_;

  int krow[4], kcol[4], vrow[4], vcol[4];
#pragma unroll
  for (int it = 0; it < 4; it++) {
    int i = it * 256 + tid;
    krow[it] = i >> 4;  kcol[it] = (i & 15) * 8;
    vrow[it] = i >> 3;  vcol[it] = (i & 7) * 8;
  }

  // Q fragments (B-operand of S^T mfma): m=l15, d=lq*8+j
  half8 qf[2][4];
#pragma unroll
  for (int i = 0; i < 2; i++)
#pragma unroll
    for (int kd = 0; kd < 4; kd++)
      qf[i][kd] = *(const half8*)(Q + (size_t)(b * S_ + q0 + wave * 32 + i * 16 + l15) * HID_
                                  + h * HD_ + kd * 32 + lq * 8);

  float m_i[2] = {-3.0e38f, -3.0e38f};
  float l_p[2] = {0.f, 0.f};   // per-lane partial of l
  floatx4 oacc[2][8];
#pragma unroll
  for (int i = 0; i < 2; i++)
#pragma unroll
    for (int jd = 0; jd < 8; jd++) oacc[i][jd] = (floatx4){0.f, 0.f, 0.f, 0.f};

  half8 kreg[4], vreg[4];
  // prologue: tile 0 -> regs -> buf 0
#pragma unroll
  for (int it = 0; it < 4; it++) {
    kreg[it] = *(const half8*)(Kb + (size_t)krow[it] * HD_ + kcol[it]);
    vreg[it] = *(const half8*)(VT + (size_t)vrow[it] * S_ + vcol[it]);
  }
#pragma unroll
  for (int it = 0; it < 4; it++) {
    *(half8*)&Ks[0][krow[it]][kcol[it]] = kreg[it];
    *(half8*)&Vt[0][vrow[it]][vcol[it]] = vreg[it];
  }
  __syncthreads();

  for (int t = 0; t < NT; t++) {
    const int cur = t & 1;
    const int n0  = t * BN;
    const bool has_next = (t + 1) < NT;

    if (has_next) {
      const int nn = n0 + BN;
#pragma unroll
      for (int it = 0; it < 4; it++) {
        kreg[it] = *(const half8*)(Kb + (size_t)(nn + krow[it]) * HD_ + kcol[it]);
        vreg[it] = *(const half8*)(VT + (size_t)vrow[it] * S_ + nn + vcol[it]);
      }
    }

    int4 mk4[4];
#pragma unroll
    for (int j = 0; j < 4; j++)
      mk4[j] = *(const int4*)(mb + n0 + j * 16 + lq * 4);

    // ---- S^T = K Q^T : st[j][i], n = j*16+lq*4+r, m = i*16+l15 (+wave*32)
    floatx4 st[4][2];
#pragma unroll
    for (int j = 0; j < 4; j++)
#pragma unroll
      for (int i = 0; i < 2; i++) st[j][i] = (floatx4){0.f, 0.f, 0.f, 0.f};
#pragma unroll
    for (int kd = 0; kd < 4; kd++) {
      half8 kb[4];
#pragma unroll
      for (int j = 0; j < 4; j++)
        kb[j] = *(const half8*)&Ks[cur][j * 16 + l15][kd * 32 + lq * 8];
#pragma unroll
      for (int j = 0; j < 4; j++)
#pragma unroll
        for (int i = 0; i < 2; i++)
          st[j][i] = __builtin_amdgcn_mfma_f32_16x16x32_f16(kb[j], qf[i][kd], st[j][i], 0, 0, 0);
    }

    floatx4 amf[4];
#pragma unroll
    for (int j = 0; j < 4; j++) {
      amf[j][0] = mk4[j].x ? 0.f : -3.0e38f;
      amf[j][1] = mk4[j].y ? 0.f : -3.0e38f;
      amf[j][2] = mk4[j].z ? 0.f : -3.0e38f;
      amf[j][3] = mk4[j].w ? 0.f : -3.0e38f;
    }

    // ---- online softmax (2 shfls for max; defer-max THR=8; l as lane partial)
    half4 ph[2][4];
#pragma unroll
    for (int i = 0; i < 2; i++) {
      float mx = -3.0e38f;
#pragma unroll
      for (int j = 0; j < 4; j++)
#pragma unroll
        for (int r = 0; r < 4; r++) {
          float v = st[j][i][r] * sl2e + amf[j][r];
          st[j][i][r] = v;
          mx = fmaxf(mx, v);
        }
      mx = fmaxf(mx, __shfl_xor(mx, 16));
      mx = fmaxf(mx, __shfl_xor(mx, 32));
      if (!__all(mx <= m_i[i] + 8.0f)) {
        float mnew  = fmaxf(m_i[i], mx);
        float alpha = __builtin_amdgcn_exp2f(m_i[i] - mnew);
        m_i[i] = mnew;
        l_p[i] *= alpha;
#pragma unroll
        for (int r = 0; r < 4; r++) {
          float a_r = __shfl(alpha, lq * 4 + r);
#pragma unroll
          for (int jd = 0; jd < 8; jd++) oacc[i][jd][r] *= a_r;
        }
      }
      float rs = 0.f;
#pragma unroll
      for (int j = 0; j < 4; j++)
#pragma unroll
        for (int r = 0; r < 4; r++) {
          float pv = __builtin_amdgcn_exp2f(st[j][i][r] - m_i[i]);
          ph[i][j][r] = (_Float16)pv;
          rs += pv;
        }
      l_p[i] += rs;
    }

    // ---- O += P V via 16x16x16 (A = ph in-register, B = Vt half4)
#pragma unroll
    for (int j = 0; j < 4; j++) {
#pragma unroll
      for (int jd = 0; jd < 8; jd++) {
        half4 vb = *(const half4*)&Vt[cur][jd * 16 + l15][j * 16 + lq * 4];
#pragma unroll
        for (int i = 0; i < 2; i++)
          oacc[i][jd] = __builtin_amdgcn_mfma_f32_16x16x16f16(ph[i][j], vb, oacc[i][jd], 0, 0, 0);
      }
    }

    if (has_next) {
      const int nxt = 1 - cur;
#pragma unroll
      for (int it = 0; it < 4; it++) {
        *(half8*)&Ks[nxt][krow[it]][kcol[it]] = kreg[it];
        *(half8*)&Vt[nxt][vrow[it]][vcol[it]] = vreg[it];
      }
    }
    __syncthreads();
  }

  // ---- final l reduction + epilogue
#pragma unroll
  for (int i = 0; i < 2; i++) {
    float l = l_p[i];
    l += __shfl_xor(l, 16);
    l += __shfl_xor(l, 32);
    float linv = 1.0f / l;
#pragma unroll
    for (int r = 0; r < 4; r++) {
      float lr = __shfl(linv, lq * 4 + r);
      size_t row = (size_t)(b * S_ + q0 + wave * 32 + i * 16 + lq * 4 + r);
#pragma unroll
      for (int jd = 0; jd < 8; jd++)
        Obuf[row * HID_ + h * HD_ + jd * 16 + l15] = (_Float16)(oacc[i][jd][r] * lr);
    }
  }
}

// ---------------------------------------------------------------------------
extern "C" void kernel_launch(void* const* d_in, const int* in_sizes, int n_in,
                              void* d_out, int out_size, void* d_ws, size_t ws_size,
                              hipStream_t stream) {
  const float* hidden = (const float*)d_in[0];
  const int*   mask   = (const int*)d_in[1];
  const float* Wq = (const float*)d_in[2];
  const float* bq = (const float*)d_in[3];
  const float* Wk = (const float*)d_in[4];
  const float* bk = (const float*)d_in[5];
  const float* Wv = (const float*)d_in[6];
  const float* bv = (const float*)d_in[7];
  const float* Wo = (const float*)d_in[8];
  const float* bo = (const float*)d_in[9];
  float* out = (float*)d_out;

  char* p = (char*)d_ws;
  auto alloc = [&](size_t bytes) {
    char* r = p;
    p += (bytes + 255) & ~(size_t)255;
    return r;
  };
  _Float16* hidh  = (_Float16*)alloc((size_t)M_ * HID_ * 2);
  _Float16* Wqh   = (_Float16*)alloc((size_t)HID_ * HID_ * 2);
  _Float16* Wkh   = (_Float16*)alloc((size_t)HD_ * HID_ * 2);
  _Float16* Wvh   = (_Float16*)alloc((size_t)HD_ * HID_ * 2);
  _Float16* Woh   = (_Float16*)alloc((size_t)HID_ * HID_ * 2);
  _Float16* Qh    = (_Float16*)alloc((size_t)M_ * HID_ * 2);
  _Float16* Kh    = (_Float16*)alloc((size_t)M_ * HD_ * 2);
  _Float16* VhT   = (_Float16*)alloc((size_t)M_ * HD_ * 2);
  _Float16* attnh = (_Float16*)alloc((size_t)M_ * HID_ * 2);

  // one fused fp32 -> fp16 cast (8448 blocks)
  cvt_all<<<8448, 256, 0, stream>>>(hidden, Wq, Wk, Wv, Wo,
                                    hidh, Wqh, Wkh, Wvh, Woh);

  // fused Q/K/V projection (V written transposed): 18 x 32 tiles
  dim3 gqkv(18, M_ / 128);
  gemm_qkv<<<gqkv, 256, 0, stream>>>(hidh, Wqh, bq, Qh, Wkh, bk, Kh, Wvh, bv, VhT);

  // attention (S^T flash, dbuf K/V): 128 q-rows/block, 4 waves
  dim3 ga(S_ / 128, B_ * NH_);  // (16, 32)
  attn_mfma<<<ga, 256, 0, stream>>>(Qh, Kh, VhT, mask, attnh);

  // output projection -> d_out (fp32)
  dim3 go(HID_ / 128, M_ / 128);
  gemm_out<<<go, 256, 0, stream>>>(attnh, Woh, bo, out);
}